// Round 15
// baseline (68.008 us; speedup 1.0000x reference)
//
#include <hip/hip_runtime.h>
#include <stdint.h>

#define BB 8
#define SS 2048
#define DIN 768
#define DKV 64
#define NCHUNK (DIN / 32)   // 24 k-chunks of 32
#define NSTEP (DIN / 64)    // 12 K-steps of 64 floats (2 chunks each)

typedef float f32x4 __attribute__((ext_vector_type(4)));
typedef float f32x16 __attribute__((ext_vector_type(16)));
typedef __bf16 bf16x8 __attribute__((ext_vector_type(8)));
typedef int i32x4 __attribute__((ext_vector_type(4)));
typedef float f32x2 __attribute__((ext_vector_type(2)));

#define AS1(p) ((const __attribute__((address_space(1))) uint32_t*)(p))
#define AS3(p) ((__attribute__((address_space(3))) uint32_t*)(p))

// ---------------------------------------------------------------------------
// Kernel 0: pre-convert W (f32, [64,768]) to bf16 MFMA-B fragment layout.
// ---------------------------------------------------------------------------
__global__ void wconv_kernel(const float* __restrict__ Wq,
                             const float* __restrict__ Wk,
                             const float* __restrict__ Wv,
                             __bf16* __restrict__ wf)
{
    const int m = blockIdx.y;
    const float* W = (m == 0) ? Wq : (m == 1) ? Wk : Wv;
    const int kc = blockIdx.x;
    const int t = threadIdx.x;
    const int c = t >> 6, lane = t & 63;
    const int lo = lane & 15, hi = lane >> 4;
    const float* src = W + (size_t)(16 * c + lo) * DIN + 32 * kc + 8 * hi;
    bf16x8 v;
    #pragma unroll
    for (int j = 0; j < 8; j++) v[j] = (__bf16)src[j];
    *(bf16x8*)(wf + ((((size_t)m * NCHUNK + kc) * 4 + c) * 64 + lane) * 8) = v;
}

// ---------------------------------------------------------------------------
// Kernel 1: fused projections — r8 barrier-free pipeline; epilogue writes
// K and V in MFMA-FRAGMENT layout (kfrag/vfrag) so attn's loads are
// lane-contiguous (r13/r14: row-scattered loads were TA-transaction-bound).
// ---------------------------------------------------------------------------
__global__ __launch_bounds__(256, 3) void proj_kernel(
    const float* __restrict__ Aq, const float* __restrict__ Ak, const float* __restrict__ Av,
    const __bf16* __restrict__ wf,
    const float* __restrict__ bq, const float* __restrict__ bk, const float* __restrict__ bv,
    __bf16* __restrict__ q_ws, __bf16* __restrict__ kfrag, __bf16* __restrict__ vfrag)
{
    __shared__ __align__(16) float abuf[2][64][64];   // 32 KB, per-wave slices

    const int which = blockIdx.y;
    const float* A; const float* bias;
    if (which == 0)      { A = Aq; bias = bq; }
    else if (which == 1) { A = Ak; bias = bk; }
    else                 { A = Av; bias = bv; }
    const __bf16* wfm = wf + (size_t)which * NCHUNK * 4 * 64 * 8;

    const int w = threadIdx.x >> 6;
    const int lane = threadIdx.x & 63;
    const int lo = lane & 15, hi = lane >> 4;
    const int brow = blockIdx.x * 64;

    const int srl = 16 * w + (lane >> 4);          // staging row (+4j)
    const float* asrc = A + (size_t)(brow + srl) * DIN;

    #define STAGE(t, bsel) do { \
        _Pragma("unroll") \
        for (int j = 0; j < 4; j++) { \
            const int u_ = (lane & 15) ^ ((srl + 4 * j) & 15); \
            const float* s_ = asrc + (size_t)(4 * j) * DIN + (t) * 64 + u_ * 4; \
            __builtin_amdgcn_global_load_lds(AS1(s_), AS3(&abuf[bsel][16 * w + 4 * j][0]), 16, 0, 0); \
        } } while (0)

    #define LOADW8(t, dst) do { \
        const __bf16* p_ = wfm + (((size_t)(2 * (t)) * 256) + lane) * 8; \
        _Pragma("unroll") \
        for (int c_ = 0; c_ < 4; c_++) dst[c_]     = *(const bf16x8*)(p_ + c_ * 512); \
        _Pragma("unroll") \
        for (int c_ = 0; c_ < 4; c_++) dst[4 + c_] = *(const bf16x8*)(p_ + 2048 + c_ * 512); \
    } while (0)

    #define WAIT12() do { \
        __builtin_amdgcn_sched_barrier(0); \
        asm volatile("s_waitcnt vmcnt(12)" ::: "memory"); \
        __builtin_amdgcn_sched_barrier(0); \
    } while (0)

    #define COMPUTE(bsel, wreg) do { \
        const float* lp_ = &abuf[bsel][16 * w + lo][0]; \
        _Pragma("unroll") \
        for (int cc_ = 0; cc_ < 2; cc_++) { \
            const int u0_ = 8 * cc_ + 2 * hi; \
            f32x4 a0_ = *(const f32x4*)(lp_ + 4 * (u0_ ^ lo)); \
            f32x4 a1_ = *(const f32x4*)(lp_ + 4 * ((u0_ + 1) ^ lo)); \
            bf16x8 af_; \
            _Pragma("unroll") \
            for (int j_ = 0; j_ < 4; j_++) { af_[j_] = (__bf16)a0_[j_]; af_[4 + j_] = (__bf16)a1_[j_]; } \
            _Pragma("unroll") \
            for (int c_ = 0; c_ < 4; c_++) \
                acc[c_] = __builtin_amdgcn_mfma_f32_16x16x32_bf16(af_, wreg[4 * cc_ + c_], acc[c_], 0, 0, 0); \
        } } while (0)

    bf16x8 wA[8], wB[8];
    f32x4 acc[4] = {};

    LOADW8(0, wA); STAGE(0, 0);

    #pragma unroll 1
    for (int td = 0; td < NSTEP / 2; ++td) {
        const int t0 = 2 * td, t1 = t0 + 1;
        LOADW8(t1, wB); STAGE(t1, 1);
        WAIT12();
        COMPUTE(0, wA);
        const int t2 = (t0 + 2 < NSTEP) ? t0 + 2 : t0;
        LOADW8(t2, wA); STAGE(t2, 0);
        WAIT12();
        COMPUTE(1, wB);
    }
    #undef STAGE
    #undef LOADW8
    #undef WAIT12
    #undef COMPUTE

    const int orow_base = brow + 16 * w + 4 * hi;
    #pragma unroll
    for (int c = 0; c < 4; c++) {
        const int col = lo + 16 * c;
        const float bcol = bias[col];
        #pragma unroll
        for (int r = 0; r < 4; r++) {
            const int orow = orow_base + r;
            const float val = acc[c][r] + bcol;
            const int b = orow >> 11;
            const int s = orow & 2047;
            if (which == 0) {
                q_ws[((size_t)b * SS + s) * DKV + col] = (__bf16)val;
            } else if (which == 1) {
                kfrag[((size_t)b * 64 + (s >> 5)) * 2048 + (col >> 4) * 512
                      + ((((col >> 3) & 1) << 5) + (s & 31)) * 8 + (col & 7)] = (__bf16)val;
            } else {
                vfrag[((size_t)b * 64 + (s >> 5)) * 2048
                      + ((((s >> 4) & 1) << 1) + (col >> 5)) * 512
                      + ((((s >> 3) & 1) << 5) + (col & 31)) * 8 + (s & 7)] = (__bf16)val;
            }
        }
    }
}

// ---------------------------------------------------------------------------
// Kernel 2: flash attention v7 — v6 + zero-extra-reg async-STAGE rotation:
// loadK(t+1) issues right after QK(t) consumes kA (covered by softmax+PV);
// loadV(t+1) right after PV(t) consumes vA (covered by QK+softmax of t+1).
// sched_barrier(0) pins each issue point (compiler otherwise sinks loads to
// just-before-use).  Mask int4s hoisted to iter top (parallel with QK).
// Same registers -> same occupancy as v6; (512,4).
// ---------------------------------------------------------------------------
#define NW 8
#define CEXP 0.18033688011f    // 0.125 * log2(e)

__device__ inline uint32_t pk2(float a, float b) {
    union { __bf16 h[2]; uint32_t u; } z;
    z.h[0] = (__bf16)a; z.h[1] = (__bf16)b;
    return z.u;
}

__global__ __launch_bounds__(512, 4) void attn_kernel(
    const __bf16* __restrict__ q_ws, const __bf16* __restrict__ kfrag,
    const __bf16* __restrict__ vfrag, const int* __restrict__ mask,
    float* __restrict__ out)
{
    __shared__ float ml_lds[NW][2][32];     // 2 KB
    __shared__ float o_lds[NW][32][33];     // 33 KB (stride 33: bank-clean)

    const int b = blockIdx.x & 7;              // batch == XCD (round-robin)
    const int qbase = (blockIdx.x >> 3) * 32;
    const int w = threadIdx.x >> 6;
    const int lane = threadIdx.x & 63;
    const int lq = lane & 31;
    const int h = lane >> 5;
    const int* mrow = mask + b * SS;

    bf16x8 qbf[4];
    {
        const __bf16* qp = q_ws + ((size_t)b * SS + qbase + lq) * DKV + 8 * h;
        #pragma unroll
        for (int t = 0; t < 4; t++) qbf[t] = *(const bf16x8*)(qp + 16 * t);
    }

    const __bf16* kfb = kfrag + (size_t)b * 64 * 2048 + lane * 8;
    const __bf16* vfb = vfrag + (size_t)b * 64 * 2048 + lane * 8;

    f32x16 oacc0 = {}, oacc1 = {};
    float m = -3e38f, l = 0.f;
    float pm = m * CEXP;

    // ---- prologue: tile 0 K/V into rotating registers ----
    bf16x8 kA[4], vA[4];
    {
        const size_t tb0 = (size_t)(w * 256 >> 5) * 2048;
        #pragma unroll
        for (int t = 0; t < 4; t++) kA[t] = *(const bf16x8*)(kfb + tb0 + t * 512);
        #pragma unroll
        for (int s = 0; s < 4; s++) vA[s] = *(const bf16x8*)(vfb + tb0 + s * 512);
    }

    #pragma unroll 1
    for (int it = 0; it < 8; ++it) {
        const int kv = w * 256 + it * 32;
        // next-tile base (clamped at tail: harmless dead reload of tile 7)
        const size_t tbn = (size_t)((it < 7 ? kv + 32 : kv) >> 5) * 2048;

        // ---- mask loads hoisted (independent of K; issue with QK chain) ----
        i32x4 mv[4];
        #pragma unroll
        for (int g = 0; g < 4; g++)
            mv[g] = *(const i32x4*)(mrow + kv + 8 * g + 4 * h);

        // ---- QK^T from kA ----
        f32x16 acc = {};
        #pragma unroll
        for (int t = 0; t < 4; t++)
            acc = __builtin_amdgcn_mfma_f32_32x32x16_bf16(kA[t], qbf[t], acc, 0, 0, 0);

        // ---- issue loadK(t+1) NOW (old kA dead); pin with sched_barrier ----
        #pragma unroll
        for (int t = 0; t < 4; t++) kA[t] = *(const bf16x8*)(kfb + tbn + t * 512);
        __builtin_amdgcn_sched_barrier(0);

        // ---- mask ----
        #pragma unroll
        for (int g = 0; g < 4; g++) {
            #pragma unroll
            for (int r = 0; r < 4; r++)
                acc[4 * g + r] = mv[g][r] ? -8e30f : acc[4 * g + r];
        }

        // ---- block max + defer-rescale (T13) ----
        {
            float q0 = fmaxf(fmaxf(acc[0], acc[1]),  fmaxf(acc[2], acc[3]));
            float q1 = fmaxf(fmaxf(acc[4], acc[5]),  fmaxf(acc[6], acc[7]));
            float q2 = fmaxf(fmaxf(acc[8], acc[9]),  fmaxf(acc[10], acc[11]));
            float q3 = fmaxf(fmaxf(acc[12], acc[13]), fmaxf(acc[14], acc[15]));
            float mx = fmaxf(fmaxf(q0, q1), fmaxf(q2, q3));
            mx = fmaxf(mx, __shfl_xor(mx, 32));
            if (__any((mx - m) * CEXP > 3.0f)) {
                const float mnew = fmaxf(m, mx);
                const float alpha = exp2f((m - mnew) * CEXP);
                l *= alpha;
                #pragma unroll
                for (int r = 0; r < 16; r++) { oacc0[r] *= alpha; oacc1[r] *= alpha; }
                m = mnew; pm = m * CEXP;
            }
        }

        // ---- P = exp2(fma) in place ----
        #pragma unroll
        for (int r = 0; r < 16; r++) {
            acc[r] = exp2f(fmaf(acc[r], CEXP, -pm));
            l += acc[r];
        }

        // ---- pack + half-exchange + PV from vA ----
        #pragma unroll
        for (int s = 0; s < 2; s++) {
            const uint32_t X0 = pk2(acc[8*s+0], acc[8*s+1]);
            const uint32_t X1 = pk2(acc[8*s+2], acc[8*s+3]);
            const uint32_t Y0 = pk2(acc[8*s+4], acc[8*s+5]);
            const uint32_t Y1 = pk2(acc[8*s+6], acc[8*s+7]);
            const uint32_t t0 = h ? X0 : Y0;
            const uint32_t t1 = h ? X1 : Y1;
            const uint32_t c0 = __shfl_xor(t0, 32);
            const uint32_t c1 = __shfl_xor(t1, 32);
            union { uint32_t wd[4]; bf16x8 v; } fr;
            fr.wd[0] = h ? c0 : X0;
            fr.wd[1] = h ? c1 : X1;
            fr.wd[2] = h ? Y0 : c0;
            fr.wd[3] = h ? Y1 : c1;

            oacc0 = __builtin_amdgcn_mfma_f32_32x32x16_bf16(vA[2 * s],     fr.v, oacc0, 0, 0, 0);
            oacc1 = __builtin_amdgcn_mfma_f32_32x32x16_bf16(vA[2 * s + 1], fr.v, oacc1, 0, 0, 0);
        }

        // ---- issue loadV(t+1) NOW (vA dead); pin ----
        #pragma unroll
        for (int s = 0; s < 4; s++) vA[s] = *(const bf16x8*)(vfb + tbn + s * 512);
        __builtin_amdgcn_sched_barrier(0);
    }

    l += __shfl_xor(l, 32);

    // ---- publish phase 1: m, l, oacc0 (v 0..31) ----
    if (h == 0) { ml_lds[w][0][lq] = m; ml_lds[w][1][lq] = l; }
    #pragma unroll
    for (int r = 0; r < 16; r++) {
        const int v = (r & 3) + 8 * (r >> 2) + 4 * h;
        o_lds[w][lq][v] = oacc0[r];
    }
    __syncthreads();

    const int row = threadIdx.x >> 4;
    const int c0  = (threadIdx.x & 15) * 2;
    float M = -3e38f;
    #pragma unroll
    for (int ww = 0; ww < NW; ww++) M = fmaxf(M, ml_lds[ww][0][row]);
    float L = 0.f;
    float a[NW];
    #pragma unroll
    for (int ww = 0; ww < NW; ww++) {
        a[ww] = exp2f((ml_lds[ww][0][row] - M) * CEXP);
        L += ml_lds[ww][1][row] * a[ww];
    }
    const float invL = 1.0f / L;
    float* op = out + ((size_t)b * SS + qbase + row) * DKV;
    {
        float s0 = 0.f, s1 = 0.f;
        #pragma unroll
        for (int ww = 0; ww < NW; ww++) {
            s0 += o_lds[ww][row][c0]     * a[ww];
            s1 += o_lds[ww][row][c0 + 1] * a[ww];
        }
        f32x2 st; st[0] = s0 * invL; st[1] = s1 * invL;
        *(f32x2*)(op + c0) = st;
    }
    __syncthreads();

    #pragma unroll
    for (int r = 0; r < 16; r++) {
        const int v = (r & 3) + 8 * (r >> 2) + 4 * h;
        o_lds[w][lq][v] = oacc1[r];
    }
    __syncthreads();
    {
        float s0 = 0.f, s1 = 0.f;
        #pragma unroll
        for (int ww = 0; ww < NW; ww++) {
            s0 += o_lds[ww][row][c0]     * a[ww];
            s1 += o_lds[ww][row][c0 + 1] * a[ww];
        }
        f32x2 st; st[0] = s0 * invL; st[1] = s1 * invL;
        *(f32x2*)(op + 32 + c0) = st;
    }
}

extern "C" void kernel_launch(void* const* d_in, const int* in_sizes, int n_in,
                              void* d_out, int out_size, void* d_ws, size_t ws_size,
                              hipStream_t stream)
{
    (void)in_sizes; (void)n_in; (void)out_size; (void)ws_size;
    const float* query = (const float*)d_in[0];
    const float* key_  = (const float*)d_in[1];
    const float* value = (const float*)d_in[2];
    const int*   mask  = (const int*)d_in[3];
    const float* Wq    = (const float*)d_in[4];
    const float* bq    = (const float*)d_in[5];
    const float* Wk    = (const float*)d_in[6];
    const float* bk    = (const float*)d_in[7];
    const float* Wv    = (const float*)d_in[8];
    const float* bv    = (const float*)d_in[9];
    float* out = (float*)d_out;

    __bf16* q_ws  = (__bf16*)d_ws;                         // 2 MB
    __bf16* kfrag = q_ws + (size_t)BB * SS * DKV;          // 2 MB (frag layout)
    __bf16* vfrag = kfrag + (size_t)BB * SS * DKV;         // 2 MB (frag layout)
    __bf16* wf    = vfrag + (size_t)BB * SS * DKV;         // 3 x 98 KB frag-W

    wconv_kernel<<<dim3(NCHUNK, 3, 1), 256, 0, stream>>>(Wq, Wk, Wv, wf);
    proj_kernel<<<dim3(256, 3, 1), 256, 0, stream>>>(
        query, key_, value, wf, bq, bk, bv, q_ws, kfrag, vfrag);
    attn_kernel<<<dim3(SS / 32 * BB, 1, 1), 512, 0, stream>>>(
        q_ws, kfrag, vfrag, mask, out);
}

// Round 16
// 58.235 us; speedup vs baseline: 1.1678x; 1.1678x over previous
//
#include <hip/hip_runtime.h>
#include <stdint.h>

#define BB 8
#define SS 2048
#define DIN 768
#define DKV 64
#define NCHUNK (DIN / 32)   // 24 k-chunks of 32
#define NSTEP (DIN / 64)    // 12 K-steps of 64 floats (2 chunks each)

typedef float f32x4 __attribute__((ext_vector_type(4)));
typedef float f32x16 __attribute__((ext_vector_type(16)));
typedef __bf16 bf16x8 __attribute__((ext_vector_type(8)));
typedef int i32x4 __attribute__((ext_vector_type(4)));
typedef float f32x2 __attribute__((ext_vector_type(2)));

#define AS1(p) ((const __attribute__((address_space(1))) uint32_t*)(p))
#define AS3(p) ((__attribute__((address_space(3))) uint32_t*)(p))

// ---------------------------------------------------------------------------
// Kernel 0: pre-convert W (f32, [64,768]) to bf16 MFMA-B fragment layout.
// ---------------------------------------------------------------------------
__global__ void wconv_kernel(const float* __restrict__ Wq,
                             const float* __restrict__ Wk,
                             const float* __restrict__ Wv,
                             __bf16* __restrict__ wf)
{
    const int m = blockIdx.y;
    const float* W = (m == 0) ? Wq : (m == 1) ? Wk : Wv;
    const int kc = blockIdx.x;
    const int t = threadIdx.x;
    const int c = t >> 6, lane = t & 63;
    const int lo = lane & 15, hi = lane >> 4;
    const float* src = W + (size_t)(16 * c + lo) * DIN + 32 * kc + 8 * hi;
    bf16x8 v;
    #pragma unroll
    for (int j = 0; j < 8; j++) v[j] = (__bf16)src[j];
    *(bf16x8*)(wf + ((((size_t)m * NCHUNK + kc) * 4 + c) * 64 + lane) * 8) = v;
}

// ---------------------------------------------------------------------------
// Kernel 1: fused projections — r8 barrier-free pipeline; epilogue writes
// K and V in MFMA-FRAGMENT layout (kfrag/vfrag) so attn's loads are
// lane-contiguous (r13/r14: row-scattered loads were TA-transaction-bound).
// ---------------------------------------------------------------------------
__global__ __launch_bounds__(256, 3) void proj_kernel(
    const float* __restrict__ Aq, const float* __restrict__ Ak, const float* __restrict__ Av,
    const __bf16* __restrict__ wf,
    const float* __restrict__ bq, const float* __restrict__ bk, const float* __restrict__ bv,
    __bf16* __restrict__ q_ws, __bf16* __restrict__ kfrag, __bf16* __restrict__ vfrag)
{
    __shared__ __align__(16) float abuf[2][64][64];   // 32 KB, per-wave slices

    const int which = blockIdx.y;
    const float* A; const float* bias;
    if (which == 0)      { A = Aq; bias = bq; }
    else if (which == 1) { A = Ak; bias = bk; }
    else                 { A = Av; bias = bv; }
    const __bf16* wfm = wf + (size_t)which * NCHUNK * 4 * 64 * 8;

    const int w = threadIdx.x >> 6;
    const int lane = threadIdx.x & 63;
    const int lo = lane & 15, hi = lane >> 4;
    const int brow = blockIdx.x * 64;

    const int srl = 16 * w + (lane >> 4);          // staging row (+4j)
    const float* asrc = A + (size_t)(brow + srl) * DIN;

    #define STAGE(t, bsel) do { \
        _Pragma("unroll") \
        for (int j = 0; j < 4; j++) { \
            const int u_ = (lane & 15) ^ ((srl + 4 * j) & 15); \
            const float* s_ = asrc + (size_t)(4 * j) * DIN + (t) * 64 + u_ * 4; \
            __builtin_amdgcn_global_load_lds(AS1(s_), AS3(&abuf[bsel][16 * w + 4 * j][0]), 16, 0, 0); \
        } } while (0)

    #define LOADW8(t, dst) do { \
        const __bf16* p_ = wfm + (((size_t)(2 * (t)) * 256) + lane) * 8; \
        _Pragma("unroll") \
        for (int c_ = 0; c_ < 4; c_++) dst[c_]     = *(const bf16x8*)(p_ + c_ * 512); \
        _Pragma("unroll") \
        for (int c_ = 0; c_ < 4; c_++) dst[4 + c_] = *(const bf16x8*)(p_ + 2048 + c_ * 512); \
    } while (0)

    #define WAIT12() do { \
        __builtin_amdgcn_sched_barrier(0); \
        asm volatile("s_waitcnt vmcnt(12)" ::: "memory"); \
        __builtin_amdgcn_sched_barrier(0); \
    } while (0)

    #define COMPUTE(bsel, wreg) do { \
        const float* lp_ = &abuf[bsel][16 * w + lo][0]; \
        _Pragma("unroll") \
        for (int cc_ = 0; cc_ < 2; cc_++) { \
            const int u0_ = 8 * cc_ + 2 * hi; \
            f32x4 a0_ = *(const f32x4*)(lp_ + 4 * (u0_ ^ lo)); \
            f32x4 a1_ = *(const f32x4*)(lp_ + 4 * ((u0_ + 1) ^ lo)); \
            bf16x8 af_; \
            _Pragma("unroll") \
            for (int j_ = 0; j_ < 4; j_++) { af_[j_] = (__bf16)a0_[j_]; af_[4 + j_] = (__bf16)a1_[j_]; } \
            _Pragma("unroll") \
            for (int c_ = 0; c_ < 4; c_++) \
                acc[c_] = __builtin_amdgcn_mfma_f32_16x16x32_bf16(af_, wreg[4 * cc_ + c_], acc[c_], 0, 0, 0); \
        } } while (0)

    bf16x8 wA[8], wB[8];
    f32x4 acc[4] = {};

    LOADW8(0, wA); STAGE(0, 0);

    #pragma unroll 1
    for (int td = 0; td < NSTEP / 2; ++td) {
        const int t0 = 2 * td, t1 = t0 + 1;
        LOADW8(t1, wB); STAGE(t1, 1);
        WAIT12();
        COMPUTE(0, wA);
        const int t2 = (t0 + 2 < NSTEP) ? t0 + 2 : t0;
        LOADW8(t2, wA); STAGE(t2, 0);
        WAIT12();
        COMPUTE(1, wB);
    }
    #undef STAGE
    #undef LOADW8
    #undef WAIT12
    #undef COMPUTE

    const int orow_base = brow + 16 * w + 4 * hi;
    #pragma unroll
    for (int c = 0; c < 4; c++) {
        const int col = lo + 16 * c;
        const float bcol = bias[col];
        #pragma unroll
        for (int r = 0; r < 4; r++) {
            const int orow = orow_base + r;
            const float val = acc[c][r] + bcol;
            const int b = orow >> 11;
            const int s = orow & 2047;
            if (which == 0) {
                q_ws[((size_t)b * SS + s) * DKV + col] = (__bf16)val;
            } else if (which == 1) {
                kfrag[((size_t)b * 64 + (s >> 5)) * 2048 + (col >> 4) * 512
                      + ((((col >> 3) & 1) << 5) + (s & 31)) * 8 + (col & 7)] = (__bf16)val;
            } else {
                vfrag[((size_t)b * 64 + (s >> 5)) * 2048
                      + ((((s >> 4) & 1) << 1) + (col >> 5)) * 512
                      + ((((s >> 3) & 1) << 5) + (col & 31)) * 8 + (s & 7)] = (__bf16)val;
            }
        }
    }
}

// ---------------------------------------------------------------------------
// Kernel 2: flash attention v6b — r14's v6 (best known: fragment-layout K/V,
// defer-rescale, fma-folded exp2, two-phase combine, (512,4)) with ONE
// residual from v7: mask int4 loads hoisted above the QK chain (independent
// loads issue in parallel with MFMAs; no fences, no register rotation —
// r15's rotation+sched_barrier lengthened the serial chain and regressed).
// ---------------------------------------------------------------------------
#define NW 8
#define CEXP 0.18033688011f    // 0.125 * log2(e)

__device__ inline uint32_t pk2(float a, float b) {
    union { __bf16 h[2]; uint32_t u; } z;
    z.h[0] = (__bf16)a; z.h[1] = (__bf16)b;
    return z.u;
}

__global__ __launch_bounds__(512, 4) void attn_kernel(
    const __bf16* __restrict__ q_ws, const __bf16* __restrict__ kfrag,
    const __bf16* __restrict__ vfrag, const int* __restrict__ mask,
    float* __restrict__ out)
{
    __shared__ float ml_lds[NW][2][32];     // 2 KB
    __shared__ float o_lds[NW][32][33];     // 33 KB (stride 33: bank-clean)

    const int b = blockIdx.x & 7;              // batch == XCD (round-robin)
    const int qbase = (blockIdx.x >> 3) * 32;
    const int w = threadIdx.x >> 6;
    const int lane = threadIdx.x & 63;
    const int lq = lane & 31;
    const int h = lane >> 5;
    const int* mrow = mask + b * SS;

    bf16x8 qbf[4];
    {
        const __bf16* qp = q_ws + ((size_t)b * SS + qbase + lq) * DKV + 8 * h;
        #pragma unroll
        for (int t = 0; t < 4; t++) qbf[t] = *(const bf16x8*)(qp + 16 * t);
    }

    const __bf16* kfb = kfrag + (size_t)b * 64 * 2048 + lane * 8;
    const __bf16* vfb = vfrag + (size_t)b * 64 * 2048 + lane * 8;

    f32x16 oacc0 = {}, oacc1 = {};   // D[v][q], v-halves 0-31 / 32-63
    float m = -3e38f, l = 0.f;
    float pm = m * CEXP;

    #pragma unroll 1
    for (int it = 0; it < 8; ++it) {
        const int kv = w * 256 + it * 32;
        const size_t tb = (size_t)(kv >> 5) * 2048;

        // ---- mask loads hoisted: independent, issue alongside QK chain ----
        i32x4 mv[4];
        #pragma unroll
        for (int g = 0; g < 4; g++)
            mv[g] = *(const i32x4*)(mrow + kv + 8 * g + 4 * h);

        // ---- QK^T: coalesced fragment loads (lane*8 contiguous) ----
        f32x16 acc = {};
        #pragma unroll
        for (int t = 0; t < 4; t++) {
            bf16x8 kaf = *(const bf16x8*)(kfb + tb + t * 512);
            acc = __builtin_amdgcn_mfma_f32_32x32x16_bf16(kaf, qbf[t], acc, 0, 0, 0);
        }

        // ---- mask ----
        #pragma unroll
        for (int g = 0; g < 4; g++) {
            #pragma unroll
            for (int r = 0; r < 4; r++)
                acc[4 * g + r] = mv[g][r] ? -8e30f : acc[4 * g + r];
        }

        // ---- block max + defer-rescale (T13) ----
        {
            float q0 = fmaxf(fmaxf(acc[0], acc[1]),  fmaxf(acc[2], acc[3]));
            float q1 = fmaxf(fmaxf(acc[4], acc[5]),  fmaxf(acc[6], acc[7]));
            float q2 = fmaxf(fmaxf(acc[8], acc[9]),  fmaxf(acc[10], acc[11]));
            float q3 = fmaxf(fmaxf(acc[12], acc[13]), fmaxf(acc[14], acc[15]));
            float mx = fmaxf(fmaxf(q0, q1), fmaxf(q2, q3));
            mx = fmaxf(mx, __shfl_xor(mx, 32));
            if (__any((mx - m) * CEXP > 3.0f)) {
                const float mnew = fmaxf(m, mx);
                const float alpha = exp2f((m - mnew) * CEXP);
                l *= alpha;
                #pragma unroll
                for (int r = 0; r < 16; r++) { oacc0[r] *= alpha; oacc1[r] *= alpha; }
                m = mnew; pm = m * CEXP;
            }
        }

        // ---- P = exp2(fma) in place ----
        #pragma unroll
        for (int r = 0; r < 16; r++) {
            acc[r] = exp2f(fmaf(acc[r], CEXP, -pm));
            l += acc[r];
        }

        // ---- pack + half-exchange + PV (coalesced V frags) ----
        #pragma unroll
        for (int s = 0; s < 2; s++) {
            const uint32_t X0 = pk2(acc[8*s+0], acc[8*s+1]);
            const uint32_t X1 = pk2(acc[8*s+2], acc[8*s+3]);
            const uint32_t Y0 = pk2(acc[8*s+4], acc[8*s+5]);
            const uint32_t Y1 = pk2(acc[8*s+6], acc[8*s+7]);
            const uint32_t t0 = h ? X0 : Y0;
            const uint32_t t1 = h ? X1 : Y1;
            const uint32_t c0 = __shfl_xor(t0, 32);
            const uint32_t c1 = __shfl_xor(t1, 32);
            union { uint32_t wd[4]; bf16x8 v; } fr;
            fr.wd[0] = h ? c0 : X0;
            fr.wd[1] = h ? c1 : X1;
            fr.wd[2] = h ? Y0 : c0;
            fr.wd[3] = h ? Y1 : c1;

            bf16x8 va0 = *(const bf16x8*)(vfb + tb + (2 * s) * 512);
            bf16x8 va1 = *(const bf16x8*)(vfb + tb + (2 * s + 1) * 512);
            oacc0 = __builtin_amdgcn_mfma_f32_32x32x16_bf16(va0, fr.v, oacc0, 0, 0, 0);
            oacc1 = __builtin_amdgcn_mfma_f32_32x32x16_bf16(va1, fr.v, oacc1, 0, 0, 0);
        }
    }

    l += __shfl_xor(l, 32);   // partner holds the other key-half's sum

    // ---- publish phase 1: m, l, oacc0 (v 0..31) ----
    if (h == 0) { ml_lds[w][0][lq] = m; ml_lds[w][1][lq] = l; }
    #pragma unroll
    for (int r = 0; r < 16; r++) {
        const int v = (r & 3) + 8 * (r >> 2) + 4 * h;
        o_lds[w][lq][v] = oacc0[r];
    }
    __syncthreads();

    // ---- combine: thread -> (row, col-pair); alphas kept in regs ----
    const int row = threadIdx.x >> 4;          // 0..31
    const int c0  = (threadIdx.x & 15) * 2;    // 0,2,..,30
    float M = -3e38f;
    #pragma unroll
    for (int ww = 0; ww < NW; ww++) M = fmaxf(M, ml_lds[ww][0][row]);
    float L = 0.f;
    float a[NW];
    #pragma unroll
    for (int ww = 0; ww < NW; ww++) {
        a[ww] = exp2f((ml_lds[ww][0][row] - M) * CEXP);
        L += ml_lds[ww][1][row] * a[ww];
    }
    const float invL = 1.0f / L;
    float* op = out + ((size_t)b * SS + qbase + row) * DKV;
    {
        float s0 = 0.f, s1 = 0.f;
        #pragma unroll
        for (int ww = 0; ww < NW; ww++) {
            s0 += o_lds[ww][row][c0]     * a[ww];
            s1 += o_lds[ww][row][c0 + 1] * a[ww];
        }
        f32x2 st; st[0] = s0 * invL; st[1] = s1 * invL;
        *(f32x2*)(op + c0) = st;
    }
    __syncthreads();

    // ---- publish phase 2: oacc1 (v 32..63) into the same slots ----
    #pragma unroll
    for (int r = 0; r < 16; r++) {
        const int v = (r & 3) + 8 * (r >> 2) + 4 * h;
        o_lds[w][lq][v] = oacc1[r];
    }
    __syncthreads();
    {
        float s0 = 0.f, s1 = 0.f;
        #pragma unroll
        for (int ww = 0; ww < NW; ww++) {
            s0 += o_lds[ww][row][c0]     * a[ww];
            s1 += o_lds[ww][row][c0 + 1] * a[ww];
        }
        f32x2 st; st[0] = s0 * invL; st[1] = s1 * invL;
        *(f32x2*)(op + 32 + c0) = st;
    }
}

extern "C" void kernel_launch(void* const* d_in, const int* in_sizes, int n_in,
                              void* d_out, int out_size, void* d_ws, size_t ws_size,
                              hipStream_t stream)
{
    (void)in_sizes; (void)n_in; (void)out_size; (void)ws_size;
    const float* query = (const float*)d_in[0];
    const float* key_  = (const float*)d_in[1];
    const float* value = (const float*)d_in[2];
    const int*   mask  = (const int*)d_in[3];
    const float* Wq    = (const float*)d_in[4];
    const float* bq    = (const float*)d_in[5];
    const float* Wk    = (const float*)d_in[6];
    const float* bk    = (const float*)d_in[7];
    const float* Wv    = (const float*)d_in[8];
    const float* bv    = (const float*)d_in[9];
    float* out = (float*)d_out;

    __bf16* q_ws  = (__bf16*)d_ws;                         // 2 MB
    __bf16* kfrag = q_ws + (size_t)BB * SS * DKV;          // 2 MB (frag layout)
    __bf16* vfrag = kfrag + (size_t)BB * SS * DKV;         // 2 MB (frag layout)
    __bf16* wf    = vfrag + (size_t)BB * SS * DKV;         // 3 x 98 KB frag-W

    wconv_kernel<<<dim3(NCHUNK, 3, 1), 256, 0, stream>>>(Wq, Wk, Wv, wf);
    proj_kernel<<<dim3(256, 3, 1), 256, 0, stream>>>(
        query, key_, value, wf, bq, bk, bv, q_ws, kfrag, vfrag);
    attn_kernel<<<dim3(SS / 32 * BB, 1, 1), 512, 0, stream>>>(
        q_ws, kfrag, vfrag, mask, out);
}

// Round 17
// 53.382 us; speedup vs baseline: 1.2740x; 1.0909x over previous
//
#include <hip/hip_runtime.h>
#include <stdint.h>

#define BB 8
#define SS 2048
#define DIN 768
#define DKV 64
#define NCHUNK (DIN / 32)   // 24 k-chunks of 32
#define NSTEP (DIN / 64)    // 12 K-steps of 64 floats (2 chunks each)

typedef float f32x4 __attribute__((ext_vector_type(4)));
typedef float f32x16 __attribute__((ext_vector_type(16)));
typedef __bf16 bf16x8 __attribute__((ext_vector_type(8)));
typedef float f32x2 __attribute__((ext_vector_type(2)));

#define AS1(p) ((const __attribute__((address_space(1))) uint32_t*)(p))
#define AS3(p) ((__attribute__((address_space(3))) uint32_t*)(p))

// ---------------------------------------------------------------------------
// Kernel -1: key compaction.  rank[b][s] = position of key s among unmasked
// keys (order-preserving), or -1 if masked; cnt[b] = number of unmasked keys.
// Masked keys contribute exactly 0 to softmax (exp underflow) in both the
// reference and v6b, so attention need only visit the ~50% unmasked keys.
// ---------------------------------------------------------------------------
__global__ __launch_bounds__(256) void compact_kernel(
    const int* __restrict__ mask, int* __restrict__ rank, int* __restrict__ cnt)
{
    const int b = blockIdx.x;
    const int t = threadIdx.x;
    __shared__ int psum[256];
    const int* mrow = mask + b * SS;
    int keep[8], loc[8], c = 0;
    #pragma unroll
    for (int j = 0; j < 8; j++) {
        keep[j] = (mrow[t * 8 + j] == 0);
        loc[j] = c;
        c += keep[j];
    }
    psum[t] = c;
    __syncthreads();
    if (t == 0) {
        int run = 0;
        for (int i = 0; i < 256; i++) { int v = psum[i]; psum[i] = run; run += v; }
        cnt[b] = run;
    }
    __syncthreads();
    const int base = psum[t];
    #pragma unroll
    for (int j = 0; j < 8; j++)
        rank[b * SS + t * 8 + j] = keep[j] ? (base + loc[j]) : -1;
}

// ---------------------------------------------------------------------------
// Kernel 0: pre-convert W (f32, [64,768]) to bf16 MFMA-B fragment layout.
// ---------------------------------------------------------------------------
__global__ void wconv_kernel(const float* __restrict__ Wq,
                             const float* __restrict__ Wk,
                             const float* __restrict__ Wv,
                             __bf16* __restrict__ wf)
{
    const int m = blockIdx.y;
    const float* W = (m == 0) ? Wq : (m == 1) ? Wk : Wv;
    const int kc = blockIdx.x;
    const int t = threadIdx.x;
    const int c = t >> 6, lane = t & 63;
    const int lo = lane & 15, hi = lane >> 4;
    const float* src = W + (size_t)(16 * c + lo) * DIN + 32 * kc + 8 * hi;
    bf16x8 v;
    #pragma unroll
    for (int j = 0; j < 8; j++) v[j] = (__bf16)src[j];
    *(bf16x8*)(wf + ((((size_t)m * NCHUNK + kc) * 4 + c) * 64 + lane) * 8) = v;
}

// ---------------------------------------------------------------------------
// Kernel 1: fused projections — r8 barrier-free pipeline; K/V epilogue now
// writes fragments at COMPACTED key positions (rank[s]); masked keys skipped.
// ---------------------------------------------------------------------------
__global__ __launch_bounds__(256, 3) void proj_kernel(
    const float* __restrict__ Aq, const float* __restrict__ Ak, const float* __restrict__ Av,
    const __bf16* __restrict__ wf, const int* __restrict__ rank,
    const float* __restrict__ bq, const float* __restrict__ bk, const float* __restrict__ bv,
    __bf16* __restrict__ q_ws, __bf16* __restrict__ kfrag, __bf16* __restrict__ vfrag)
{
    __shared__ __align__(16) float abuf[2][64][64];   // 32 KB, per-wave slices

    const int which = blockIdx.y;
    const float* A; const float* bias;
    if (which == 0)      { A = Aq; bias = bq; }
    else if (which == 1) { A = Ak; bias = bk; }
    else                 { A = Av; bias = bv; }
    const __bf16* wfm = wf + (size_t)which * NCHUNK * 4 * 64 * 8;

    const int w = threadIdx.x >> 6;
    const int lane = threadIdx.x & 63;
    const int lo = lane & 15, hi = lane >> 4;
    const int brow = blockIdx.x * 64;

    const int srl = 16 * w + (lane >> 4);          // staging row (+4j)
    const float* asrc = A + (size_t)(brow + srl) * DIN;

    #define STAGE(t, bsel) do { \
        _Pragma("unroll") \
        for (int j = 0; j < 4; j++) { \
            const int u_ = (lane & 15) ^ ((srl + 4 * j) & 15); \
            const float* s_ = asrc + (size_t)(4 * j) * DIN + (t) * 64 + u_ * 4; \
            __builtin_amdgcn_global_load_lds(AS1(s_), AS3(&abuf[bsel][16 * w + 4 * j][0]), 16, 0, 0); \
        } } while (0)

    #define LOADW8(t, dst) do { \
        const __bf16* p_ = wfm + (((size_t)(2 * (t)) * 256) + lane) * 8; \
        _Pragma("unroll") \
        for (int c_ = 0; c_ < 4; c_++) dst[c_]     = *(const bf16x8*)(p_ + c_ * 512); \
        _Pragma("unroll") \
        for (int c_ = 0; c_ < 4; c_++) dst[4 + c_] = *(const bf16x8*)(p_ + 2048 + c_ * 512); \
    } while (0)

    #define WAIT12() do { \
        __builtin_amdgcn_sched_barrier(0); \
        asm volatile("s_waitcnt vmcnt(12)" ::: "memory"); \
        __builtin_amdgcn_sched_barrier(0); \
    } while (0)

    #define COMPUTE(bsel, wreg) do { \
        const float* lp_ = &abuf[bsel][16 * w + lo][0]; \
        _Pragma("unroll") \
        for (int cc_ = 0; cc_ < 2; cc_++) { \
            const int u0_ = 8 * cc_ + 2 * hi; \
            f32x4 a0_ = *(const f32x4*)(lp_ + 4 * (u0_ ^ lo)); \
            f32x4 a1_ = *(const f32x4*)(lp_ + 4 * ((u0_ + 1) ^ lo)); \
            bf16x8 af_; \
            _Pragma("unroll") \
            for (int j_ = 0; j_ < 4; j_++) { af_[j_] = (__bf16)a0_[j_]; af_[4 + j_] = (__bf16)a1_[j_]; } \
            _Pragma("unroll") \
            for (int c_ = 0; c_ < 4; c_++) \
                acc[c_] = __builtin_amdgcn_mfma_f32_16x16x32_bf16(af_, wreg[4 * cc_ + c_], acc[c_], 0, 0, 0); \
        } } while (0)

    bf16x8 wA[8], wB[8];
    f32x4 acc[4] = {};

    LOADW8(0, wA); STAGE(0, 0);

    #pragma unroll 1
    for (int td = 0; td < NSTEP / 2; ++td) {
        const int t0 = 2 * td, t1 = t0 + 1;
        LOADW8(t1, wB); STAGE(t1, 1);
        WAIT12();
        COMPUTE(0, wA);
        const int t2 = (t0 + 2 < NSTEP) ? t0 + 2 : t0;
        LOADW8(t2, wA); STAGE(t2, 0);
        WAIT12();
        COMPUTE(1, wB);
    }
    #undef STAGE
    #undef LOADW8
    #undef WAIT12
    #undef COMPUTE

    const int orow_base = brow + 16 * w + 4 * hi;
    if (which == 0) {
        #pragma unroll
        for (int c = 0; c < 4; c++) {
            const int col = lo + 16 * c;
            const float bcol = bias[col];
            #pragma unroll
            for (int r = 0; r < 4; r++) {
                const int orow = orow_base + r;
                const int b = orow >> 11, s = orow & 2047;
                q_ws[((size_t)b * SS + s) * DKV + col] = (__bf16)(acc[c][r] + bcol);
            }
        }
    } else if (which == 1) {
        #pragma unroll
        for (int r = 0; r < 4; r++) {
            const int orow = orow_base + r;
            const int b = orow >> 11, s = orow & 2047;
            const int rk = rank[b * SS + s];
            if (rk >= 0) {
                #pragma unroll
                for (int c = 0; c < 4; c++) {
                    const int col = lo + 16 * c;
                    const float val = acc[c][r] + bias[col];
                    kfrag[((size_t)b * 64 + (rk >> 5)) * 2048 + (col >> 4) * 512
                          + ((((col >> 3) & 1) << 5) + (rk & 31)) * 8 + (col & 7)] = (__bf16)val;
                }
            }
        }
    } else {
        #pragma unroll
        for (int r = 0; r < 4; r++) {
            const int orow = orow_base + r;
            const int b = orow >> 11, s = orow & 2047;
            const int rk = rank[b * SS + s];
            if (rk >= 0) {
                #pragma unroll
                for (int c = 0; c < 4; c++) {
                    const int col = lo + 16 * c;
                    const float val = acc[c][r] + bias[col];
                    vfrag[((size_t)b * 64 + (rk >> 5)) * 2048
                          + ((((rk >> 4) & 1) << 1) + (col >> 5)) * 512
                          + ((((rk >> 3) & 1) << 5) + (col & 31)) * 8 + (rk & 7)] = (__bf16)val;
                }
            }
        }
    }
}

// ---------------------------------------------------------------------------
// Kernel 2: flash attention v8 — v6b over the COMPACTED key set: nt =
// ceil(cnt/32) tiles split across 8 waves; no mask loads or cndmasks in the
// loop; only the final tile applies a tail bias (key >= cnt -> -8e30, P
// underflows to exact +0 so padded/stale V contributes nothing).  Empty
// waves publish m=-3e38,l=0 and vanish in the combine.
// ---------------------------------------------------------------------------
#define NW 8
#define CEXP 0.18033688011f    // 0.125 * log2(e)

__device__ inline uint32_t pk2(float a, float b) {
    union { __bf16 h[2]; uint32_t u; } z;
    z.h[0] = (__bf16)a; z.h[1] = (__bf16)b;
    return z.u;
}

__global__ __launch_bounds__(512, 4) void attn_kernel(
    const __bf16* __restrict__ q_ws, const __bf16* __restrict__ kfrag,
    const __bf16* __restrict__ vfrag, const int* __restrict__ cnt,
    float* __restrict__ out)
{
    __shared__ float ml_lds[NW][2][32];     // 2 KB
    __shared__ float o_lds[NW][32][33];     // 33 KB (stride 33: bank-clean)

    const int b = blockIdx.x & 7;              // batch == XCD (round-robin)
    const int qbase = (blockIdx.x >> 3) * 32;
    const int w = threadIdx.x >> 6;
    const int lane = threadIdx.x & 63;
    const int lq = lane & 31;
    const int h = lane >> 5;

    bf16x8 qbf[4];
    {
        const __bf16* qp = q_ws + ((size_t)b * SS + qbase + lq) * DKV + 8 * h;
        #pragma unroll
        for (int t = 0; t < 4; t++) qbf[t] = *(const bf16x8*)(qp + 16 * t);
    }

    const __bf16* kfb = kfrag + (size_t)b * 64 * 2048 + lane * 8;
    const __bf16* vfb = vfrag + (size_t)b * 64 * 2048 + lane * 8;

    const int cnt_b = cnt[b];
    const int nt = (cnt_b + 31) >> 5;
    const int ntpw = (nt + NW - 1) >> 3;
    const int it0 = w * ntpw;
    const int it1 = (it0 + ntpw < nt) ? it0 + ntpw : nt;

    f32x16 oacc0 = {}, oacc1 = {};   // D[v][q], v-halves 0-31 / 32-63
    float m = -3e38f, l = 0.f;
    float pm = m * CEXP;

    #pragma unroll 1
    for (int it = it0; it < it1; ++it) {
        const size_t tb = (size_t)it * 2048;

        // ---- QK^T: coalesced fragment loads (lane*8 contiguous) ----
        f32x16 acc = {};
        #pragma unroll
        for (int t = 0; t < 4; t++) {
            bf16x8 kaf = *(const bf16x8*)(kfb + tb + t * 512);
            acc = __builtin_amdgcn_mfma_f32_32x32x16_bf16(kaf, qbf[t], acc, 0, 0, 0);
        }

        // ---- tail bias: only the last (partial) tile pays this ----
        if (((it + 1) << 5) > cnt_b) {
            #pragma unroll
            for (int r = 0; r < 16; r++) {
                const int key = (it << 5) + (r & 3) + 8 * (r >> 2) + 4 * h;
                if (key >= cnt_b) acc[r] = -8e30f;
            }
        }

        // ---- block max + defer-rescale (T13) ----
        {
            float q0 = fmaxf(fmaxf(acc[0], acc[1]),  fmaxf(acc[2], acc[3]));
            float q1 = fmaxf(fmaxf(acc[4], acc[5]),  fmaxf(acc[6], acc[7]));
            float q2 = fmaxf(fmaxf(acc[8], acc[9]),  fmaxf(acc[10], acc[11]));
            float q3 = fmaxf(fmaxf(acc[12], acc[13]), fmaxf(acc[14], acc[15]));
            float mx = fmaxf(fmaxf(q0, q1), fmaxf(q2, q3));
            mx = fmaxf(mx, __shfl_xor(mx, 32));
            if (__any((mx - m) * CEXP > 3.0f)) {
                const float mnew = fmaxf(m, mx);
                const float alpha = exp2f((m - mnew) * CEXP);
                l *= alpha;
                #pragma unroll
                for (int r = 0; r < 16; r++) { oacc0[r] *= alpha; oacc1[r] *= alpha; }
                m = mnew; pm = m * CEXP;
            }
        }

        // ---- P = exp2(fma) in place ----
        #pragma unroll
        for (int r = 0; r < 16; r++) {
            acc[r] = exp2f(fmaf(acc[r], CEXP, -pm));
            l += acc[r];
        }

        // ---- pack + half-exchange + PV (coalesced V frags) ----
        #pragma unroll
        for (int s = 0; s < 2; s++) {
            const uint32_t X0 = pk2(acc[8*s+0], acc[8*s+1]);
            const uint32_t X1 = pk2(acc[8*s+2], acc[8*s+3]);
            const uint32_t Y0 = pk2(acc[8*s+4], acc[8*s+5]);
            const uint32_t Y1 = pk2(acc[8*s+6], acc[8*s+7]);
            const uint32_t t0 = h ? X0 : Y0;
            const uint32_t t1 = h ? X1 : Y1;
            const uint32_t c0 = __shfl_xor(t0, 32);
            const uint32_t c1 = __shfl_xor(t1, 32);
            union { uint32_t wd[4]; bf16x8 v; } fr;
            fr.wd[0] = h ? c0 : X0;
            fr.wd[1] = h ? c1 : X1;
            fr.wd[2] = h ? Y0 : c0;
            fr.wd[3] = h ? Y1 : c1;

            bf16x8 va0 = *(const bf16x8*)(vfb + tb + (2 * s) * 512);
            bf16x8 va1 = *(const bf16x8*)(vfb + tb + (2 * s + 1) * 512);
            oacc0 = __builtin_amdgcn_mfma_f32_32x32x16_bf16(va0, fr.v, oacc0, 0, 0, 0);
            oacc1 = __builtin_amdgcn_mfma_f32_32x32x16_bf16(va1, fr.v, oacc1, 0, 0, 0);
        }
    }

    l += __shfl_xor(l, 32);   // partner holds the other key-half's sum

    // ---- publish phase 1: m, l, oacc0 (v 0..31) ----
    if (h == 0) { ml_lds[w][0][lq] = m; ml_lds[w][1][lq] = l; }
    #pragma unroll
    for (int r = 0; r < 16; r++) {
        const int v = (r & 3) + 8 * (r >> 2) + 4 * h;
        o_lds[w][lq][v] = oacc0[r];
    }
    __syncthreads();

    // ---- combine: thread -> (row, col-pair); alphas kept in regs ----
    const int row = threadIdx.x >> 4;          // 0..31
    const int c0  = (threadIdx.x & 15) * 2;    // 0,2,..,30
    float M = -3e38f;
    #pragma unroll
    for (int ww = 0; ww < NW; ww++) M = fmaxf(M, ml_lds[ww][0][row]);
    float L = 0.f;
    float a[NW];
    #pragma unroll
    for (int ww = 0; ww < NW; ww++) {
        a[ww] = exp2f((ml_lds[ww][0][row] - M) * CEXP);
        L += ml_lds[ww][1][row] * a[ww];
    }
    const float invL = 1.0f / L;
    float* op = out + ((size_t)b * SS + qbase + row) * DKV;
    {
        float s0 = 0.f, s1 = 0.f;
        #pragma unroll
        for (int ww = 0; ww < NW; ww++) {
            s0 += o_lds[ww][row][c0]     * a[ww];
            s1 += o_lds[ww][row][c0 + 1] * a[ww];
        }
        f32x2 st; st[0] = s0 * invL; st[1] = s1 * invL;
        *(f32x2*)(op + c0) = st;
    }
    __syncthreads();

    // ---- publish phase 2: oacc1 (v 32..63) into the same slots ----
    #pragma unroll
    for (int r = 0; r < 16; r++) {
        const int v = (r & 3) + 8 * (r >> 2) + 4 * h;
        o_lds[w][lq][v] = oacc1[r];
    }
    __syncthreads();
    {
        float s0 = 0.f, s1 = 0.f;
        #pragma unroll
        for (int ww = 0; ww < NW; ww++) {
            s0 += o_lds[ww][row][c0]     * a[ww];
            s1 += o_lds[ww][row][c0 + 1] * a[ww];
        }
        f32x2 st; st[0] = s0 * invL; st[1] = s1 * invL;
        *(f32x2*)(op + 32 + c0) = st;
    }
}

extern "C" void kernel_launch(void* const* d_in, const int* in_sizes, int n_in,
                              void* d_out, int out_size, void* d_ws, size_t ws_size,
                              hipStream_t stream)
{
    (void)in_sizes; (void)n_in; (void)out_size; (void)ws_size;
    const float* query = (const float*)d_in[0];
    const float* key_  = (const float*)d_in[1];
    const float* value = (const float*)d_in[2];
    const int*   mask  = (const int*)d_in[3];
    const float* Wq    = (const float*)d_in[4];
    const float* bq    = (const float*)d_in[5];
    const float* Wk    = (const float*)d_in[6];
    const float* bk    = (const float*)d_in[7];
    const float* Wv    = (const float*)d_in[8];
    const float* bv    = (const float*)d_in[9];
    float* out = (float*)d_out;

    __bf16* q_ws  = (__bf16*)d_ws;                         // 2 MB
    __bf16* kfrag = q_ws + (size_t)BB * SS * DKV;          // 2 MB (frag layout)
    __bf16* vfrag = kfrag + (size_t)BB * SS * DKV;         // 2 MB (frag layout)
    __bf16* wf    = vfrag + (size_t)BB * SS * DKV;         // 288 KB frag-W
    int* rank     = (int*)(wf + (size_t)3 * NCHUNK * 4 * 64 * 8);  // 64 KB
    int* cnt      = rank + BB * SS;                        // 32 B

    compact_kernel<<<dim3(BB, 1, 1), 256, 0, stream>>>(mask, rank, cnt);
    wconv_kernel<<<dim3(NCHUNK, 3, 1), 256, 0, stream>>>(Wq, Wk, Wv, wf);
    proj_kernel<<<dim3(256, 3, 1), 256, 0, stream>>>(
        query, key_, value, wf, rank, bq, bk, bv, q_ws, kfrag, vfrag);
    attn_kernel<<<dim3(SS / 32 * BB, 1, 1), 512, 0, stream>>>(
        q_ws, kfrag, vfrag, cnt, out);
}

// Round 18
// 51.767 us; speedup vs baseline: 1.3137x; 1.0312x over previous
//
#include <hip/hip_runtime.h>
#include <stdint.h>

#define BB 8
#define SS 2048
#define DIN 768
#define DKV 64
#define NCHUNK (DIN / 32)   // 24 k-chunks of 32
#define NSTEP (DIN / 64)    // 12 K-steps of 64 floats (2 chunks each)

typedef float f32x4 __attribute__((ext_vector_type(4)));
typedef float f32x16 __attribute__((ext_vector_type(16)));
typedef __bf16 bf16x8 __attribute__((ext_vector_type(8)));
typedef float f32x2 __attribute__((ext_vector_type(2)));

#define AS1(p) ((const __attribute__((address_space(1))) uint32_t*)(p))
#define AS3(p) ((__attribute__((address_space(3))) uint32_t*)(p))

// ---------------------------------------------------------------------------
// Kernel 0: prep — fuses W fragment-convert (blockIdx.y<3) and per-batch
// mask compaction (blockIdx.y==3, blockIdx.x<BB) into one launch (r17 had
// them as two full-device round-trips; compact was 8 blocks for 8 KB work).
// ---------------------------------------------------------------------------
__global__ __launch_bounds__(256) void prep_kernel(
    const float* __restrict__ Wq, const float* __restrict__ Wk,
    const float* __restrict__ Wv, __bf16* __restrict__ wf,
    const int* __restrict__ mask, int* __restrict__ rank, int* __restrict__ cnt)
{
    if (blockIdx.y < 3) {
        const int m = blockIdx.y;
        const float* W = (m == 0) ? Wq : (m == 1) ? Wk : Wv;
        const int kc = blockIdx.x;
        const int t = threadIdx.x;
        const int c = t >> 6, lane = t & 63;
        const int lo = lane & 15, hi = lane >> 4;
        const float* src = W + (size_t)(16 * c + lo) * DIN + 32 * kc + 8 * hi;
        bf16x8 v;
        #pragma unroll
        for (int j = 0; j < 8; j++) v[j] = (__bf16)src[j];
        *(bf16x8*)(wf + ((((size_t)m * NCHUNK + kc) * 4 + c) * 64 + lane) * 8) = v;
        return;
    }
    // ---- compaction: rank[b][s] = order-preserving index among unmasked ----
    const int b = blockIdx.x;
    if (b >= BB) return;
    const int t = threadIdx.x;
    __shared__ int psum[256];
    const int* mrow = mask + b * SS;
    int keep[8], loc[8], c = 0;
    #pragma unroll
    for (int j = 0; j < 8; j++) {
        keep[j] = (mrow[t * 8 + j] == 0);
        loc[j] = c;
        c += keep[j];
    }
    psum[t] = c;
    __syncthreads();
    if (t == 0) {
        int run = 0;
        for (int i = 0; i < 256; i++) { int v = psum[i]; psum[i] = run; run += v; }
        cnt[b] = run;
    }
    __syncthreads();
    const int base = psum[t];
    #pragma unroll
    for (int j = 0; j < 8; j++)
        rank[b * SS + t * 8 + j] = keep[j] ? (base + loc[j]) : -1;
}

// ---------------------------------------------------------------------------
// Kernel 1: fused projections — r8 barrier-free pipeline; K/V epilogue
// writes fragments at COMPACTED key positions (rank[s]); masked keys skipped.
// (unchanged from r17)
// ---------------------------------------------------------------------------
__global__ __launch_bounds__(256, 3) void proj_kernel(
    const float* __restrict__ Aq, const float* __restrict__ Ak, const float* __restrict__ Av,
    const __bf16* __restrict__ wf, const int* __restrict__ rank,
    const float* __restrict__ bq, const float* __restrict__ bk, const float* __restrict__ bv,
    __bf16* __restrict__ q_ws, __bf16* __restrict__ kfrag, __bf16* __restrict__ vfrag)
{
    __shared__ __align__(16) float abuf[2][64][64];   // 32 KB, per-wave slices

    const int which = blockIdx.y;
    const float* A; const float* bias;
    if (which == 0)      { A = Aq; bias = bq; }
    else if (which == 1) { A = Ak; bias = bk; }
    else                 { A = Av; bias = bv; }
    const __bf16* wfm = wf + (size_t)which * NCHUNK * 4 * 64 * 8;

    const int w = threadIdx.x >> 6;
    const int lane = threadIdx.x & 63;
    const int lo = lane & 15, hi = lane >> 4;
    const int brow = blockIdx.x * 64;

    const int srl = 16 * w + (lane >> 4);          // staging row (+4j)
    const float* asrc = A + (size_t)(brow + srl) * DIN;

    #define STAGE(t, bsel) do { \
        _Pragma("unroll") \
        for (int j = 0; j < 4; j++) { \
            const int u_ = (lane & 15) ^ ((srl + 4 * j) & 15); \
            const float* s_ = asrc + (size_t)(4 * j) * DIN + (t) * 64 + u_ * 4; \
            __builtin_amdgcn_global_load_lds(AS1(s_), AS3(&abuf[bsel][16 * w + 4 * j][0]), 16, 0, 0); \
        } } while (0)

    #define LOADW8(t, dst) do { \
        const __bf16* p_ = wfm + (((size_t)(2 * (t)) * 256) + lane) * 8; \
        _Pragma("unroll") \
        for (int c_ = 0; c_ < 4; c_++) dst[c_]     = *(const bf16x8*)(p_ + c_ * 512); \
        _Pragma("unroll") \
        for (int c_ = 0; c_ < 4; c_++) dst[4 + c_] = *(const bf16x8*)(p_ + 2048 + c_ * 512); \
    } while (0)

    #define WAIT12() do { \
        __builtin_amdgcn_sched_barrier(0); \
        asm volatile("s_waitcnt vmcnt(12)" ::: "memory"); \
        __builtin_amdgcn_sched_barrier(0); \
    } while (0)

    #define COMPUTE(bsel, wreg) do { \
        const float* lp_ = &abuf[bsel][16 * w + lo][0]; \
        _Pragma("unroll") \
        for (int cc_ = 0; cc_ < 2; cc_++) { \
            const int u0_ = 8 * cc_ + 2 * hi; \
            f32x4 a0_ = *(const f32x4*)(lp_ + 4 * (u0_ ^ lo)); \
            f32x4 a1_ = *(const f32x4*)(lp_ + 4 * ((u0_ + 1) ^ lo)); \
            bf16x8 af_; \
            _Pragma("unroll") \
            for (int j_ = 0; j_ < 4; j_++) { af_[j_] = (__bf16)a0_[j_]; af_[4 + j_] = (__bf16)a1_[j_]; } \
            _Pragma("unroll") \
            for (int c_ = 0; c_ < 4; c_++) \
                acc[c_] = __builtin_amdgcn_mfma_f32_16x16x32_bf16(af_, wreg[4 * cc_ + c_], acc[c_], 0, 0, 0); \
        } } while (0)

    bf16x8 wA[8], wB[8];
    f32x4 acc[4] = {};

    LOADW8(0, wA); STAGE(0, 0);

    #pragma unroll 1
    for (int td = 0; td < NSTEP / 2; ++td) {
        const int t0 = 2 * td, t1 = t0 + 1;
        LOADW8(t1, wB); STAGE(t1, 1);
        WAIT12();
        COMPUTE(0, wA);
        const int t2 = (t0 + 2 < NSTEP) ? t0 + 2 : t0;
        LOADW8(t2, wA); STAGE(t2, 0);
        WAIT12();
        COMPUTE(1, wB);
    }
    #undef STAGE
    #undef LOADW8
    #undef WAIT12
    #undef COMPUTE

    const int orow_base = brow + 16 * w + 4 * hi;
    if (which == 0) {
        #pragma unroll
        for (int c = 0; c < 4; c++) {
            const int col = lo + 16 * c;
            const float bcol = bias[col];
            #pragma unroll
            for (int r = 0; r < 4; r++) {
                const int orow = orow_base + r;
                const int b = orow >> 11, s = orow & 2047;
                q_ws[((size_t)b * SS + s) * DKV + col] = (__bf16)(acc[c][r] + bcol);
            }
        }
    } else if (which == 1) {
        #pragma unroll
        for (int r = 0; r < 4; r++) {
            const int orow = orow_base + r;
            const int b = orow >> 11, s = orow & 2047;
            const int rk = rank[b * SS + s];
            if (rk >= 0) {
                #pragma unroll
                for (int c = 0; c < 4; c++) {
                    const int col = lo + 16 * c;
                    const float val = acc[c][r] + bias[col];
                    kfrag[((size_t)b * 64 + (rk >> 5)) * 2048 + (col >> 4) * 512
                          + ((((col >> 3) & 1) << 5) + (rk & 31)) * 8 + (col & 7)] = (__bf16)val;
                }
            }
        }
    } else {
        #pragma unroll
        for (int r = 0; r < 4; r++) {
            const int orow = orow_base + r;
            const int b = orow >> 11, s = orow & 2047;
            const int rk = rank[b * SS + s];
            if (rk >= 0) {
                #pragma unroll
                for (int c = 0; c < 4; c++) {
                    const int col = lo + 16 * c;
                    const float val = acc[c][r] + bias[col];
                    vfrag[((size_t)b * 64 + (rk >> 5)) * 2048
                          + ((((rk >> 4) & 1) << 1) + (col >> 5)) * 512
                          + ((((rk >> 3) & 1) << 5) + (col & 31)) * 8 + (rk & 7)] = (__bf16)val;
                }
            }
        }
    }
}

// ---------------------------------------------------------------------------
// Kernel 2: flash attention v8 — compacted key set (unchanged from r17).
// ---------------------------------------------------------------------------
#define NW 8
#define CEXP 0.18033688011f    // 0.125 * log2(e)

__device__ inline uint32_t pk2(float a, float b) {
    union { __bf16 h[2]; uint32_t u; } z;
    z.h[0] = (__bf16)a; z.h[1] = (__bf16)b;
    return z.u;
}

__global__ __launch_bounds__(512, 4) void attn_kernel(
    const __bf16* __restrict__ q_ws, const __bf16* __restrict__ kfrag,
    const __bf16* __restrict__ vfrag, const int* __restrict__ cnt,
    float* __restrict__ out)
{
    __shared__ float ml_lds[NW][2][32];     // 2 KB
    __shared__ float o_lds[NW][32][33];     // 33 KB (stride 33: bank-clean)

    const int b = blockIdx.x & 7;              // batch == XCD (round-robin)
    const int qbase = (blockIdx.x >> 3) * 32;
    const int w = threadIdx.x >> 6;
    const int lane = threadIdx.x & 63;
    const int lq = lane & 31;
    const int h = lane >> 5;

    bf16x8 qbf[4];
    {
        const __bf16* qp = q_ws + ((size_t)b * SS + qbase + lq) * DKV + 8 * h;
        #pragma unroll
        for (int t = 0; t < 4; t++) qbf[t] = *(const bf16x8*)(qp + 16 * t);
    }

    const __bf16* kfb = kfrag + (size_t)b * 64 * 2048 + lane * 8;
    const __bf16* vfb = vfrag + (size_t)b * 64 * 2048 + lane * 8;

    const int cnt_b = cnt[b];
    const int nt = (cnt_b + 31) >> 5;
    const int ntpw = (nt + NW - 1) >> 3;
    const int it0 = w * ntpw;
    const int it1 = (it0 + ntpw < nt) ? it0 + ntpw : nt;

    f32x16 oacc0 = {}, oacc1 = {};   // D[v][q], v-halves 0-31 / 32-63
    float m = -3e38f, l = 0.f;
    float pm = m * CEXP;

    #pragma unroll 1
    for (int it = it0; it < it1; ++it) {
        const size_t tb = (size_t)it * 2048;

        // ---- QK^T: coalesced fragment loads (lane*8 contiguous) ----
        f32x16 acc = {};
        #pragma unroll
        for (int t = 0; t < 4; t++) {
            bf16x8 kaf = *(const bf16x8*)(kfb + tb + t * 512);
            acc = __builtin_amdgcn_mfma_f32_32x32x16_bf16(kaf, qbf[t], acc, 0, 0, 0);
        }

        // ---- tail bias: only the last (partial) tile pays this ----
        if (((it + 1) << 5) > cnt_b) {
            #pragma unroll
            for (int r = 0; r < 16; r++) {
                const int key = (it << 5) + (r & 3) + 8 * (r >> 2) + 4 * h;
                if (key >= cnt_b) acc[r] = -8e30f;
            }
        }

        // ---- block max + defer-rescale (T13) ----
        {
            float q0 = fmaxf(fmaxf(acc[0], acc[1]),  fmaxf(acc[2], acc[3]));
            float q1 = fmaxf(fmaxf(acc[4], acc[5]),  fmaxf(acc[6], acc[7]));
            float q2 = fmaxf(fmaxf(acc[8], acc[9]),  fmaxf(acc[10], acc[11]));
            float q3 = fmaxf(fmaxf(acc[12], acc[13]), fmaxf(acc[14], acc[15]));
            float mx = fmaxf(fmaxf(q0, q1), fmaxf(q2, q3));
            mx = fmaxf(mx, __shfl_xor(mx, 32));
            if (__any((mx - m) * CEXP > 3.0f)) {
                const float mnew = fmaxf(m, mx);
                const float alpha = exp2f((m - mnew) * CEXP);
                l *= alpha;
                #pragma unroll
                for (int r = 0; r < 16; r++) { oacc0[r] *= alpha; oacc1[r] *= alpha; }
                m = mnew; pm = m * CEXP;
            }
        }

        // ---- P = exp2(fma) in place ----
        #pragma unroll
        for (int r = 0; r < 16; r++) {
            acc[r] = exp2f(fmaf(acc[r], CEXP, -pm));
            l += acc[r];
        }

        // ---- pack + half-exchange + PV (coalesced V frags) ----
        #pragma unroll
        for (int s = 0; s < 2; s++) {
            const uint32_t X0 = pk2(acc[8*s+0], acc[8*s+1]);
            const uint32_t X1 = pk2(acc[8*s+2], acc[8*s+3]);
            const uint32_t Y0 = pk2(acc[8*s+4], acc[8*s+5]);
            const uint32_t Y1 = pk2(acc[8*s+6], acc[8*s+7]);
            const uint32_t t0 = h ? X0 : Y0;
            const uint32_t t1 = h ? X1 : Y1;
            const uint32_t c0 = __shfl_xor(t0, 32);
            const uint32_t c1 = __shfl_xor(t1, 32);
            union { uint32_t wd[4]; bf16x8 v; } fr;
            fr.wd[0] = h ? c0 : X0;
            fr.wd[1] = h ? c1 : X1;
            fr.wd[2] = h ? Y0 : c0;
            fr.wd[3] = h ? Y1 : c1;

            bf16x8 va0 = *(const bf16x8*)(vfb + tb + (2 * s) * 512);
            bf16x8 va1 = *(const bf16x8*)(vfb + tb + (2 * s + 1) * 512);
            oacc0 = __builtin_amdgcn_mfma_f32_32x32x16_bf16(va0, fr.v, oacc0, 0, 0, 0);
            oacc1 = __builtin_amdgcn_mfma_f32_32x32x16_bf16(va1, fr.v, oacc1, 0, 0, 0);
        }
    }

    l += __shfl_xor(l, 32);   // partner holds the other key-half's sum

    // ---- publish phase 1: m, l, oacc0 (v 0..31) ----
    if (h == 0) { ml_lds[w][0][lq] = m; ml_lds[w][1][lq] = l; }
    #pragma unroll
    for (int r = 0; r < 16; r++) {
        const int v = (r & 3) + 8 * (r >> 2) + 4 * h;
        o_lds[w][lq][v] = oacc0[r];
    }
    __syncthreads();

    // ---- combine: thread -> (row, col-pair); alphas kept in regs ----
    const int row = threadIdx.x >> 4;          // 0..31
    const int c0  = (threadIdx.x & 15) * 2;    // 0,2,..,30
    float M = -3e38f;
    #pragma unroll
    for (int ww = 0; ww < NW; ww++) M = fmaxf(M, ml_lds[ww][0][row]);
    float L = 0.f;
    float a[NW];
    #pragma unroll
    for (int ww = 0; ww < NW; ww++) {
        a[ww] = exp2f((ml_lds[ww][0][row] - M) * CEXP);
        L += ml_lds[ww][1][row] * a[ww];
    }
    const float invL = 1.0f / L;
    float* op = out + ((size_t)b * SS + qbase + row) * DKV;
    {
        float s0 = 0.f, s1 = 0.f;
        #pragma unroll
        for (int ww = 0; ww < NW; ww++) {
            s0 += o_lds[ww][row][c0]     * a[ww];
            s1 += o_lds[ww][row][c0 + 1] * a[ww];
        }
        f32x2 st; st[0] = s0 * invL; st[1] = s1 * invL;
        *(f32x2*)(op + c0) = st;
    }
    __syncthreads();

    // ---- publish phase 2: oacc1 (v 32..63) into the same slots ----
    #pragma unroll
    for (int r = 0; r < 16; r++) {
        const int v = (r & 3) + 8 * (r >> 2) + 4 * h;
        o_lds[w][lq][v] = oacc1[r];
    }
    __syncthreads();
    {
        float s0 = 0.f, s1 = 0.f;
        #pragma unroll
        for (int ww = 0; ww < NW; ww++) {
            s0 += o_lds[ww][row][c0]     * a[ww];
            s1 += o_lds[ww][row][c0 + 1] * a[ww];
        }
        f32x2 st; st[0] = s0 * invL; st[1] = s1 * invL;
        *(f32x2*)(op + 32 + c0) = st;
    }
}

extern "C" void kernel_launch(void* const* d_in, const int* in_sizes, int n_in,
                              void* d_out, int out_size, void* d_ws, size_t ws_size,
                              hipStream_t stream)
{
    (void)in_sizes; (void)n_in; (void)out_size; (void)ws_size;
    const float* query = (const float*)d_in[0];
    const float* key_  = (const float*)d_in[1];
    const float* value = (const float*)d_in[2];
    const int*   mask  = (const int*)d_in[3];
    const float* Wq    = (const float*)d_in[4];
    const float* bq    = (const float*)d_in[5];
    const float* Wk    = (const float*)d_in[6];
    const float* bk    = (const float*)d_in[7];
    const float* Wv    = (const float*)d_in[8];
    const float* bv    = (const float*)d_in[9];
    float* out = (float*)d_out;

    __bf16* q_ws  = (__bf16*)d_ws;                         // 2 MB
    __bf16* kfrag = q_ws + (size_t)BB * SS * DKV;          // 2 MB (frag layout)
    __bf16* vfrag = kfrag + (size_t)BB * SS * DKV;         // 2 MB (frag layout)
    __bf16* wf    = vfrag + (size_t)BB * SS * DKV;         // 288 KB frag-W
    int* rank     = (int*)(wf + (size_t)3 * NCHUNK * 4 * 64 * 8);  // 64 KB
    int* cnt      = rank + BB * SS;                        // 32 B

    prep_kernel<<<dim3(NCHUNK, 4, 1), 256, 0, stream>>>(
        Wq, Wk, Wv, wf, mask, rank, cnt);
    proj_kernel<<<dim3(256, 3, 1), 256, 0, stream>>>(
        query, key_, value, wf, rank, bq, bk, bv, q_ws, kfrag, vfrag);
    attn_kernel<<<dim3(SS / 32 * BB, 1, 1), 512, 0, stream>>>(
        q_ws, kfrag, vfrag, cnt, out);
}